// Round 2
// baseline (295.683 us; speedup 1.0000x reference)
//
#include <hip/hip_runtime.h>

#define NC 32   // chirps
#define NS 64   // samples per chirp

// Output depends ONLY on frame[0] (see reference: mag[0]).  Single workgroup
// computes the whole 32x32 image: range DFT -> MTI -> doppler DFT -> |.|.
// Output dtype is uint8 in the reference -> harness reads d_out as int32.
__global__ __launch_bounds__(1024) void rdm_kernel(const float* __restrict__ frame,
                                                   int* __restrict__ out) {
    __shared__ float x[NC][NS];          // samples (raw, then windowed)
    __shared__ float Xre[NC][NC];        // range-FFT bins 0..31, [chirp][bin]
    __shared__ float Xim[NC][NC];
    __shared__ float rowMean[NC];
    __shared__ float colMeanRe[NC];
    __shared__ float colMeanIm[NC];
    __shared__ float twc64[64], tws64[64];   // e^{-i 2pi t/64} tables
    __shared__ float twc32[32], tws32[32];   // e^{-i 2pi t/32} tables
    __shared__ float dw[NC];                 // kaiser window (un-normalized)
    __shared__ float dwInv;                  // 1 / sum(dw)

    const int tid = threadIdx.x;
    const float PI = 3.14159265358979323846f;

    // ---- phase 0: load frame[0] (2048 floats) + build twiddles + kaiser ----
    ((float*)x)[tid]        = frame[tid];
    ((float*)x)[tid + 1024] = frame[tid + 1024];

    if (tid < 64) {
        float ang = 2.0f * PI * (float)tid * (1.0f / 64.0f);
        twc64[tid] = cosf(ang);
        tws64[tid] = sinf(ang);
    } else if (tid < 96) {
        int t = tid - 64;
        float ang = 2.0f * PI * (float)t * (1.0f / 32.0f);
        twc32[t] = cosf(ang);
        tws32[t] = sinf(ang);
    } else if (tid < 128) {
        // kaiser(32, beta=25): I0(25*sqrt(1-((c-15.5)/15.5)^2)).
        // The /I0(25) factor cancels when normalizing by the window sum.
        int c = tid - 96;
        double alpha = 15.5;
        double d = ((double)c - alpha) / alpha;
        double arg = 1.0 - d * d;
        if (arg < 0.0) arg = 0.0;
        double h = 0.5 * (25.0 * sqrt(arg));   // x/2
        double term = 1.0, sum = 1.0;          // I0 power series, converged by k=64
        for (int k2 = 1; k2 <= 64; ++k2) {
            term *= h / (double)k2;
            sum += term * term;
        }
        dw[c] = (float)sum;
    }
    __syncthreads();

    // ---- phase 1: per-chirp sample mean; kaiser normalization sum ----
    if (tid < NC) {
        float s = 0.0f;
        for (int j = 0; j < NS; ++j) s += x[tid][j];
        rowMean[tid] = s * (1.0f / NS);
    } else if (tid == NC) {
        float s = 0.0f;
        for (int c = 0; c < NC; ++c) s += dw[c];
        dwInv = 1.0f / s;
    }
    __syncthreads();

    // ---- phase 2: mean-remove + normalized hann(64, periodic=False) ----
    // sum of hann(64) = 32 - 0.5*sum cos(2pi s/63) = 31.5 exactly.
    for (int j = tid; j < NC * NS; j += 1024) {
        int c = j >> 6, s = j & 63;
        float w = (0.5f - 0.5f * cosf(2.0f * PI * (float)s * (1.0f / 63.0f))) * (1.0f / 31.5f);
        x[c][s] = (x[c][s] - rowMean[c]) * w;
    }
    __syncthreads();

    // ---- phase 3: range DFT, keep bins 0..31 (Nyquist dropped) ----
    {
        int c = tid >> 5, k = tid & 31;
        float re = 0.0f, im = 0.0f;
        for (int s = 0; s < NS; ++s) {
            int idx = (k * s) & 63;
            float v = x[c][s];
            re += v * twc64[idx];
            im -= v * tws64[idx];
        }
        Xre[c][k] = re;
        Xim[c][k] = im;
    }
    __syncthreads();

    // ---- phase 4: mean over chirps per range bin (MTI) ----
    if (tid < NC) {
        float s = 0.0f;
        for (int c = 0; c < NC; ++c) s += Xre[c][tid];
        colMeanRe[tid] = s * (1.0f / NC);
    } else if (tid < 2 * NC) {
        int k = tid - NC;
        float s = 0.0f;
        for (int c = 0; c < NC; ++c) s += Xim[c][k];
        colMeanIm[k] = s * (1.0f / NC);
    }
    __syncthreads();

    // ---- phase 4.5: MTI subtract + normalized kaiser window, in place ----
    {
        int c = tid >> 5, k = tid & 31;
        float w = dw[c] * dwInv;
        Xre[c][k] = (Xre[c][k] - colMeanRe[k]) * w;
        Xim[c][k] = (Xim[c][k] - colMeanIm[k]) * w;
    }
    __syncthreads();

    // ---- phase 5: 32-pt complex doppler DFT + |.| + shift/transpose/flip ----
    {
        int k = tid >> 5, m = tid & 31;   // k = range bin, m = doppler bin
        float zre = 0.0f, zim = 0.0f;
        for (int c = 0; c < NC; ++c) {
            int idx = (m * c) & 31;
            float cs = twc32[idx], sn = tws32[idx];
            float ur = Xre[c][k], ui = Xim[c][k];
            zre += ur * cs + ui * sn;   // (ur + i ui) * (cs - i sn)
            zim += ui * cs - ur * sn;
        }
        float mag = 1000.0f * sqrtf(zre * zre + zim * zim);
        int v = (int)(fminf(mag, 1.0f) * 255.0f);   // clip(.,0,1)*255, uint8 trunc
        // image[r][d] = mag[doppler=d][range=31-r], fftshift: Z[k][(d+16)%32]
        out[(31 - k) * 32 + ((m + 16) & 31)] = v;
    }
}

extern "C" void kernel_launch(void* const* d_in, const int* in_sizes, int n_in,
                              void* d_out, int out_size, void* d_ws, size_t ws_size,
                              hipStream_t stream) {
    const float* frame = (const float*)d_in[0];
    int* out = (int*)d_out;
    rdm_kernel<<<1, 1024, 0, stream>>>(frame, out);
}